// Round 2
// baseline (4660.164 us; speedup 1.0000x reference)
//
#include <hip/hip_runtime.h>
#include <cmath>

// LSTM decoder: B=32, T=128, D=512, UNITS=1024, VOCAB=32000.
// Round 1: phase-3 logits GEMM moved to bf16 hi/lo split-product MFMA
// (3 MFMA per product: hi*hi + hi*lo + lo*hi; fp32-class accuracy).
// Fallback to pure-fp32 path if ws_size is too small for Wd^T hi/lo.

#define BB 32
#define TT 128
#define DD 512
#define UU 1024
#define GG 4096   // 4*UU
#define VV 32000
constexpr float MASK_SCALE = 1.0f / 0.9f;

typedef __attribute__((ext_vector_type(8))) short short8_t;  // 8 bf16 (4 VGPRs)
typedef __attribute__((ext_vector_type(4))) float f32x4;

__device__ __forceinline__ unsigned short f2bf(float f) {
  unsigned u = __builtin_bit_cast(unsigned, f);
  unsigned r = (u + 0x7FFFu + ((u >> 16) & 1u)) >> 16;   // RNE
  return (unsigned short)r;
}
__device__ __forceinline__ float bf2f(unsigned short h) {
  unsigned u = ((unsigned)h) << 16;
  return __builtin_bit_cast(float, u);
}

// ---------------------------------------------------------------------------
// fp32 tiled GEMM: C[M,N] = A[M,K] @ B[K,N] + bias[N].  (phase 1 + fallback)
// 128x128 tile, 256 threads, 8x8 micro-tile, BK=8.
// ---------------------------------------------------------------------------
__global__ __launch_bounds__(256, 2) void gemm128(
    const float* __restrict__ A, const float* __restrict__ Bm,
    const float* __restrict__ bias, float* __restrict__ C,
    int M, int N, int K) {
  __shared__ float As[8][128];   // [k][m]
  __shared__ float Bs[8][128];   // [k][n]
  const int tid = threadIdx.x;
  const int m0 = blockIdx.y * 128;
  const int n0 = blockIdx.x * 128;
  const int a_r = tid >> 1, a_k4 = (tid & 1) * 4;
  const int b_k = tid >> 5, b_n4 = (tid & 31) * 4;
  const int mm = (tid & 15) * 4;
  const int nn = (tid >> 4) * 4;
  float acc[8][8];
#pragma unroll
  for (int i = 0; i < 8; ++i)
#pragma unroll
    for (int j = 0; j < 8; ++j) acc[i][j] = 0.f;

  for (int k0 = 0; k0 < K; k0 += 8) {
    const float4 av = *(const float4*)(A + (size_t)(m0 + a_r) * K + k0 + a_k4);
    const float4 bv = *(const float4*)(Bm + (size_t)(k0 + b_k) * N + n0 + b_n4);
    __syncthreads();
    As[a_k4 + 0][a_r] = av.x;
    As[a_k4 + 1][a_r] = av.y;
    As[a_k4 + 2][a_r] = av.z;
    As[a_k4 + 3][a_r] = av.w;
    *(float4*)(&Bs[b_k][b_n4]) = bv;
    __syncthreads();
#pragma unroll
    for (int k = 0; k < 8; ++k) {
      const float4 a0 = *(const float4*)(&As[k][mm]);
      const float4 a1 = *(const float4*)(&As[k][mm + 64]);
      const float4 q0 = *(const float4*)(&Bs[k][nn]);
      const float4 q1 = *(const float4*)(&Bs[k][nn + 64]);
      const float ar[8] = {a0.x, a0.y, a0.z, a0.w, a1.x, a1.y, a1.z, a1.w};
      const float br[8] = {q0.x, q0.y, q0.z, q0.w, q1.x, q1.y, q1.z, q1.w};
#pragma unroll
      for (int i = 0; i < 8; ++i)
#pragma unroll
        for (int j = 0; j < 8; ++j) acc[i][j] += ar[i] * br[j];
    }
  }
  const float4 bi0 = *(const float4*)(bias + n0 + nn);
  const float4 bi1 = *(const float4*)(bias + n0 + nn + 64);
  const float bia[8] = {bi0.x, bi0.y, bi0.z, bi0.w, bi1.x, bi1.y, bi1.z, bi1.w};
#pragma unroll
  for (int i = 0; i < 8; ++i) {
    const int m = m0 + (i < 4 ? mm + i : mm + 60 + i);
    float* cp = C + (size_t)m * N + n0;
    float4 v0 = {acc[i][0] + bia[0], acc[i][1] + bia[1], acc[i][2] + bia[2], acc[i][3] + bia[3]};
    float4 v1 = {acc[i][4] + bia[4], acc[i][5] + bia[5], acc[i][6] + bia[6], acc[i][7] + bia[7]};
    *(float4*)(cp + nn) = v0;
    *(float4*)(cp + nn + 64) = v1;
  }
}

// ---------------------------------------------------------------------------
// Wd [K=1024][N=32000] fp32  ->  Wd^T hi/lo bf16 [N][K] (k-contiguous).
// 64x64 tiles via LDS.
// ---------------------------------------------------------------------------
__global__ __launch_bounds__(256) void convert_wd(
    const float* __restrict__ Wd, unsigned short* __restrict__ Bhi,
    unsigned short* __restrict__ Blo) {
  __shared__ float tile[64][65];
  const int tid = threadIdx.x;
  const int tx = tid & 63, ty = tid >> 6;
  const int n0 = blockIdx.x * 64, k0 = blockIdx.y * 64;
#pragma unroll 4
  for (int r = 0; r < 16; ++r) {
    const int k = ty * 16 + r;
    tile[k][tx] = Wd[(size_t)(k0 + k) * VV + n0 + tx];
  }
  __syncthreads();
#pragma unroll 4
  for (int r = 0; r < 16; ++r) {
    const int n = ty * 16 + r;
    const float v = tile[tx][n];
    const unsigned short hi = f2bf(v);
    const float lof = v - bf2f(hi);
    const size_t o = (size_t)(n0 + n) * UU + k0 + tx;
    Bhi[o] = hi;
    Blo[o] = f2bf(lof);
  }
}

// ---------------------------------------------------------------------------
// Phase 3 MFMA GEMM: logits[4096][32000] = A(hi+lo) @ B(hi+lo)^T + bias.
// A: [4096][1024] bf16 hi/lo (k-contig). Bt: [32000][1024] bf16 hi/lo (k-contig).
// 128x128 tile, BK=32, 4 waves (2x2 of 64x64), 16x16x32 bf16 MFMA, 3-term split.
// LDS rows padded 32->40 bf16 (80 B stride -> 2-way bank aliasing, free).
// ---------------------------------------------------------------------------
__global__ __launch_bounds__(256, 2) void gemm_mfma_logits(
    const unsigned short* __restrict__ Ahi, const unsigned short* __restrict__ Alo,
    const unsigned short* __restrict__ Bhi, const unsigned short* __restrict__ Blo,
    const float* __restrict__ bias, float* __restrict__ C) {
  __shared__ unsigned short AsHi[128][40], AsLo[128][40];
  __shared__ unsigned short BsHi[128][40], BsLo[128][40];
  const int tid = threadIdx.x;
  const int lane = tid & 63;
  const int wave = tid >> 6;
  const int wm = wave >> 1, wn = wave & 1;   // 2x2 waves of 64x64
  const int q = lane >> 4, l15 = lane & 15;
  const int n0 = blockIdx.x * 128;
  const int m0 = blockIdx.y * 128;
  const int srow = tid >> 2;          // 0..63
  const int sk = (tid & 3) * 8;       // 0,8,16,24

  f32x4 acc[4][4];
#pragma unroll
  for (int mf = 0; mf < 4; ++mf)
#pragma unroll
    for (int nf = 0; nf < 4; ++nf) acc[mf][nf] = f32x4{0.f, 0.f, 0.f, 0.f};

  const size_t arow0 = (size_t)(m0 + srow) * UU + sk;
  const size_t arow1 = (size_t)(m0 + 64 + srow) * UU + sk;
  const size_t brow0 = (size_t)(n0 + srow) * UU + sk;
  const size_t brow1 = (size_t)(n0 + 64 + srow) * UU + sk;

  for (int k0 = 0; k0 < UU; k0 += 32) {
    const short8_t ra0h = *(const short8_t*)(Ahi + arow0 + k0);
    const short8_t ra1h = *(const short8_t*)(Ahi + arow1 + k0);
    const short8_t ra0l = *(const short8_t*)(Alo + arow0 + k0);
    const short8_t ra1l = *(const short8_t*)(Alo + arow1 + k0);
    const short8_t rb0h = *(const short8_t*)(Bhi + brow0 + k0);
    const short8_t rb1h = *(const short8_t*)(Bhi + brow1 + k0);
    const short8_t rb0l = *(const short8_t*)(Blo + brow0 + k0);
    const short8_t rb1l = *(const short8_t*)(Blo + brow1 + k0);
    __syncthreads();   // previous tile fully consumed
    *(short8_t*)&AsHi[srow][sk] = ra0h;
    *(short8_t*)&AsHi[64 + srow][sk] = ra1h;
    *(short8_t*)&AsLo[srow][sk] = ra0l;
    *(short8_t*)&AsLo[64 + srow][sk] = ra1l;
    *(short8_t*)&BsHi[srow][sk] = rb0h;
    *(short8_t*)&BsHi[64 + srow][sk] = rb1h;
    *(short8_t*)&BsLo[srow][sk] = rb0l;
    *(short8_t*)&BsLo[64 + srow][sk] = rb1l;
    __syncthreads();

    short8_t ah[4], al[4], bh[4], bl[4];
#pragma unroll
    for (int f = 0; f < 4; ++f) {
      ah[f] = *(const short8_t*)&AsHi[wm * 64 + f * 16 + l15][q * 8];
      al[f] = *(const short8_t*)&AsLo[wm * 64 + f * 16 + l15][q * 8];
      bh[f] = *(const short8_t*)&BsHi[wn * 64 + f * 16 + l15][q * 8];
      bl[f] = *(const short8_t*)&BsLo[wn * 64 + f * 16 + l15][q * 8];
    }
#pragma unroll
    for (int mf = 0; mf < 4; ++mf)
#pragma unroll
      for (int nf = 0; nf < 4; ++nf) {
        f32x4 a = acc[mf][nf];
        a = __builtin_amdgcn_mfma_f32_16x16x32_bf16(ah[mf], bh[nf], a, 0, 0, 0);
        a = __builtin_amdgcn_mfma_f32_16x16x32_bf16(ah[mf], bl[nf], a, 0, 0, 0);
        a = __builtin_amdgcn_mfma_f32_16x16x32_bf16(al[mf], bh[nf], a, 0, 0, 0);
        acc[mf][nf] = a;
      }
  }

#pragma unroll
  for (int nf = 0; nf < 4; ++nf) {
    const int n = n0 + wn * 64 + nf * 16 + l15;
    const float bia = bias[n];
#pragma unroll
    for (int mf = 0; mf < 4; ++mf) {
      const int mbase = m0 + wm * 64 + mf * 16 + q * 4;
#pragma unroll
      for (int r = 0; r < 4; ++r)
        C[(size_t)(mbase + r) * VV + n] = acc[mf][nf][r] + bia;
    }
  }
}

// ---------------------------------------------------------------------------
// Prep: transpose h0 -> hT[k][b], copy c0, bit-pack masks.
// ---------------------------------------------------------------------------
__global__ __launch_bounds__(256) void prep_kernel(
    const float* __restrict__ h0, const float* __restrict__ c0,
    const float* __restrict__ masks, float* __restrict__ hT0,
    float* __restrict__ cst, unsigned* __restrict__ mbits) {
  const int i = blockIdx.x * 256 + threadIdx.x;
  if (i < BB * UU) {
    hT0[i] = h0[(i & 31) * UU + (i >> 5)];
    cst[i] = c0[i];
  }
  if (i < 4 * UU) {
    const int g = i >> 10, k = i & 1023;
    unsigned w = 0;
#pragma unroll 4
    for (int b = 0; b < 32; ++b)
      if (masks[(size_t)(g * 32 + b) * UU + k] != 0.f) w |= (1u << b);
    mbits[i] = w;
  }
}

// ---------------------------------------------------------------------------
// One LSTM timestep. 256 blocks x 256 threads; block owns 4 u-cols x 4 gates.
// Writes h as bf16 hi/lo (fast path) or fp32 hs (fallback).
// ---------------------------------------------------------------------------
__global__ __launch_bounds__(256) void lstm_step(
    const float* __restrict__ xw,    // [B*T][4096], m = b*T + t
    const float* __restrict__ Um,    // [1024][4096]
    const float* __restrict__ hin,   // [1024][32]
    float* __restrict__ hout,        // [1024][32]
    float* __restrict__ cst,         // [32][1024]
    const unsigned* __restrict__ mbits,
    unsigned short* __restrict__ hsHi, unsigned short* __restrict__ hsLo,
    float* __restrict__ hs,
    float* __restrict__ outH, float* __restrict__ outC,
    int t) {
  __shared__ float red[256 * 17];
  const int tid = threadIdx.x;
  const int kc = tid >> 5;
  const int g = (tid >> 3) & 3;
  const int bg = tid & 7;
  const int b0 = bg * 4;
  const int ub = (blockIdx.x & 7) * 32 + (blockIdx.x >> 3);  // XCD swizzle
  const int u0 = ub * 4;

  float acc[4][4];
#pragma unroll
  for (int i = 0; i < 4; ++i)
#pragma unroll
    for (int j = 0; j < 4; ++j) acc[i][j] = 0.f;

  const unsigned* wb = mbits + g * UU;
  const int kbeg = kc * 128;
#pragma unroll 4
  for (int k = kbeg; k < kbeg + 128; ++k) {
    const float4 h4 = *(const float4*)(hin + k * 32 + b0);
    const unsigned w = wb[k];
    const float4 u4 = *(const float4*)(Um + (size_t)k * GG + g * UU + u0);
    const float hm0 = ((w >> (b0 + 0)) & 1) ? h4.x * MASK_SCALE : 0.f;
    const float hm1 = ((w >> (b0 + 1)) & 1) ? h4.y * MASK_SCALE : 0.f;
    const float hm2 = ((w >> (b0 + 2)) & 1) ? h4.z * MASK_SCALE : 0.f;
    const float hm3 = ((w >> (b0 + 3)) & 1) ? h4.w * MASK_SCALE : 0.f;
    acc[0][0] += hm0 * u4.x; acc[0][1] += hm0 * u4.y; acc[0][2] += hm0 * u4.z; acc[0][3] += hm0 * u4.w;
    acc[1][0] += hm1 * u4.x; acc[1][1] += hm1 * u4.y; acc[1][2] += hm1 * u4.z; acc[1][3] += hm1 * u4.w;
    acc[2][0] += hm2 * u4.x; acc[2][1] += hm2 * u4.y; acc[2][2] += hm2 * u4.z; acc[2][3] += hm2 * u4.w;
    acc[3][0] += hm3 * u4.x; acc[3][1] += hm3 * u4.y; acc[3][2] += hm3 * u4.z; acc[3][3] += hm3 * u4.w;
  }
#pragma unroll
  for (int i = 0; i < 4; ++i)
#pragma unroll
    for (int j = 0; j < 4; ++j) red[tid * 17 + i * 4 + j] = acc[i][j];
  __syncthreads();

  if (tid < 128) {
    const int b = tid >> 2, ul = tid & 3;
    const int u = u0 + ul;
    float z[4];
#pragma unroll
    for (int gg = 0; gg < 4; ++gg) {
      float s = 0.f;
#pragma unroll
      for (int kk = 0; kk < 8; ++kk)
        s += red[(kk * 32 + gg * 8 + (b >> 2)) * 17 + (b & 3) * 4 + ul];
      z[gg] = s + xw[((size_t)(b * TT + t)) * GG + gg * UU + u];
    }
    const float ig = 1.f / (1.f + expf(-z[0]));
    const float fg = 1.f / (1.f + expf(-z[1]));
    const float cc = tanhf(z[2]);
    const float og = 1.f / (1.f + expf(-z[3]));
    const float cold = cst[b * UU + u];
    const float cnew = fg * cold + ig * cc;
    const float hnew = og * tanhf(cnew);
    cst[b * UU + u] = cnew;
    hout[u * 32 + b] = hnew;
    const size_t idx = ((size_t)b * TT + t) * UU + u;
    if (hsHi) {
      const unsigned short hi = f2bf(hnew);
      hsHi[idx] = hi;
      hsLo[idx] = f2bf(hnew - bf2f(hi));
    } else {
      hs[idx] = hnew;
    }
    if (t == TT - 1) {
      outH[b * UU + u] = hnew;
      outC[b * UU + u] = cnew;
    }
  }
}

// ---------------------------------------------------------------------------
extern "C" void kernel_launch(void* const* d_in, const int* in_sizes, int n_in,
                              void* d_out, int out_size, void* d_ws, size_t ws_size,
                              hipStream_t stream) {
  const float* x     = (const float*)d_in[0];
  const float* h0    = (const float*)d_in[1];
  const float* c0    = (const float*)d_in[2];
  const float* W     = (const float*)d_in[3];
  const float* Um    = (const float*)d_in[4];
  const float* bvec  = (const float*)d_in[5];
  const float* Wd    = (const float*)d_in[6];
  const float* bd    = (const float*)d_in[7];
  const float* masks = (const float*)d_in[8];

  float* out = (float*)d_out;
  float* logits = out;
  float* outH = out + (size_t)BB * TT * VV;
  float* outC = outH + (size_t)BB * UU;
  float* xw = logits;   // stashed; fully consumed by the scan before phase 3

  // Fast path needs: hsHi/hsLo (16 MB) + WdHi/WdLo (125 MB) + hT/cst/mbits.
  const size_t SZ_HS   = (size_t)BB * TT * UU * 2;        // 8,388,608 B each
  const size_t SZ_WD   = (size_t)VV * UU * 2;             // 65,536,000 B each
  const size_t SZ_HT   = 2 * (size_t)UU * BB * 4;         // 262,144
  const size_t SZ_CST  = (size_t)BB * UU * 4;             // 131,072
  const size_t SZ_MB   = 4 * (size_t)UU * 4;              // 16,384
  const size_t NEED = 2 * SZ_HS + 2 * SZ_WD + SZ_HT + SZ_CST + SZ_MB;

  char* ws = (char*)d_ws;
  const bool fast = (ws_size >= NEED);

  unsigned short *hsHi = nullptr, *hsLo = nullptr, *WdHi = nullptr, *WdLo = nullptr;
  float *hs = nullptr, *hT = nullptr, *cst = nullptr;
  unsigned* mbits = nullptr;

  if (fast) {
    hsHi = (unsigned short*)ws;              ws += SZ_HS;
    hsLo = (unsigned short*)ws;              ws += SZ_HS;
    WdHi = (unsigned short*)ws;              ws += SZ_WD;
    WdLo = (unsigned short*)ws;              ws += SZ_WD;
    hT   = (float*)ws;                       ws += SZ_HT;
    cst  = (float*)ws;                       ws += SZ_CST;
    mbits = (unsigned*)ws;
  } else {
    hs   = (float*)ws;                       ws += (size_t)BB * TT * UU * 4;
    hT   = (float*)ws;                       ws += SZ_HT;
    cst  = (float*)ws;                       ws += SZ_CST;
    mbits = (unsigned*)ws;
  }

  prep_kernel<<<128, 256, 0, stream>>>(h0, c0, masks, hT, cst, mbits);

  if (fast)
    convert_wd<<<dim3(VV / 64, UU / 64), 256, 0, stream>>>(Wd, WdHi, WdLo);

  // Phase 1: xw = x @ W + b    (M=4096, N=4096, K=512), fp32 VALU GEMM
  gemm128<<<dim3(GG / 128, (BB * TT) / 128), 256, 0, stream>>>(
      x, W, bvec, xw, BB * TT, GG, DD);

  // Phase 2: 128 sequential steps
  for (int t = 0; t < TT; ++t) {
    const float* hin = hT + (size_t)(t & 1) * (UU * BB);
    float* hout      = hT + (size_t)((t + 1) & 1) * (UU * BB);
    lstm_step<<<256, 256, 0, stream>>>(xw, Um, hin, hout, cst, mbits,
                                       hsHi, hsLo, hs, outH, outC, t);
  }

  // Phase 3: logits = hs @ Wd + bd
  if (fast) {
    gemm_mfma_logits<<<dim3(VV / 128, (BB * TT) / 128), 256, 0, stream>>>(
        hsHi, hsLo, WdHi, WdLo, bd, logits);
  } else {
    gemm128<<<dim3(VV / 128, (BB * TT) / 128), 256, 0, stream>>>(
        hs, Wd, bd, logits, BB * TT, VV, UU);
  }
}